// Round 2
// baseline (411.402 us; speedup 1.0000x reference)
//
#include <hip/hip_runtime.h>
#include <string.h>

#define OUT_DIM 11008
#define IN_DIM  4096
#define NTOK    64
#define RANK    128
#define NG      32

typedef float        v4f  __attribute__((ext_vector_type(4)));
typedef int          v4i  __attribute__((ext_vector_type(4)));
typedef unsigned int v4u  __attribute__((ext_vector_type(4)));
typedef unsigned int v2u  __attribute__((ext_vector_type(2)));
typedef _Float16     v8h  __attribute__((ext_vector_type(8)));

// ---------------- K0: pack svd_down (f32 [128][4096]) into f16 row-pairs ----------------
__device__ inline unsigned int pack2h(float lo, float hi) {
  union { _Float16 h[2]; unsigned int u; } t;
  t.h[0] = (_Float16)lo; t.h[1] = (_Float16)hi;
  return t.u;
}

__global__ __launch_bounds__(256) void pack_d_kernel(const float* __restrict__ d,
                                                     unsigned int* __restrict__ dp) {
  int idx = (blockIdx.x * 256 + threadIdx.x) * 4;   // dword index
  int r2 = idx >> 12, c = idx & 4095;
  v4f a = *(const v4f*)(d + (2 * r2) * IN_DIM + c);
  v4f b = *(const v4f*)(d + (2 * r2 + 1) * IN_DIM + c);
  v4u o;
#pragma unroll
  for (int e = 0; e < 4; e++) o[e] = pack2h(a[e], b[e]);
  *(v4u*)(dp + idx) = o;
}

// ---------------- K0b: repack weight int32 -> 4-bit nibbles (180 MB -> 22.5 MB) -------
// wp[i] packs wq[8i..8i+7], nibble j = weight 8i+j (values 0..15, exact).
__global__ __launch_bounds__(256) void repack_w_kernel(const int* __restrict__ wq,
                                                       unsigned int* __restrict__ wp) {
  const int n = OUT_DIM * IN_DIM / 8;               // 5,636,096 u32 outputs
  for (int i = blockIdx.x * 256 + threadIdx.x; i < n; i += gridDim.x * 256) {
    const v4i* p = (const v4i*)(wq + i * 8);
    v4i a = p[0], b = p[1];
    unsigned int o = (unsigned)(a[0] & 15)        | ((unsigned)(a[1] & 15) << 4)
                   | ((unsigned)(a[2] & 15) << 8) | ((unsigned)(a[3] & 15) << 12)
                   | ((unsigned)(b[0] & 15) << 16)| ((unsigned)(b[1] & 15) << 20)
                   | ((unsigned)(b[2] & 15) << 24)| ((unsigned)(b[3] & 15) << 28);
    wp[i] = o;
  }
}

// ---------------- K1: dynamic-quantize x per token ----------------
__global__ __launch_bounds__(256) void quant_x_kernel(const float* __restrict__ x,
                                                      signed char* __restrict__ xq,
                                                      float* __restrict__ sx) {
  int t = blockIdx.x, tid = threadIdx.x;
  const float* row = x + t * IN_DIM;
  v4f v[4];
  float m = 0.f;
#pragma unroll
  for (int i = 0; i < 4; i++) {
    v[i] = *(const v4f*)(row + tid * 16 + i * 4);
#pragma unroll
    for (int e = 0; e < 4; e++) m = fmaxf(m, fabsf(v[i][e]));
  }
#pragma unroll
  for (int off = 1; off < 64; off <<= 1) m = fmaxf(m, __shfl_xor(m, off));
  __shared__ float wm[4];
  if ((tid & 63) == 0) wm[tid >> 6] = m;
  __syncthreads();
  m = fmaxf(fmaxf(wm[0], wm[1]), fmaxf(wm[2], wm[3]));
  float s = m / 127.0f;                      // exactly ref: max/127
  if (tid == 0) sx[t] = s;
  unsigned int packed[4];
#pragma unroll
  for (int i = 0; i < 4; i++) {
    int q[4];
#pragma unroll
    for (int e = 0; e < 4; e++) {
      float qf = rintf(v[i][e] / s);         // half-even like jnp.round
      qf = fminf(127.f, fmaxf(-128.f, qf));
      q[e] = (int)qf;
    }
    packed[i] = (q[0] & 255) | ((q[1] & 255) << 8) | ((q[2] & 255) << 16) | ((q[3] & 255) << 24);
  }
  *(v4u*)(xq + t * IN_DIM + tid * 16) = *(v4u*)packed;
}

// ---------------- shared device helpers for the two weight-pass kernels ----------------
__device__ inline void load_u(const float* __restrict__ svd_up, _Float16 (*U)[136],
                              int tid, int r0) {
#pragma unroll
  for (int i = 0; i < 16; i++) {
    int idx = i * 256 + tid;
    int r = idx >> 7, k = idx & 127;
    U[r][k] = (_Float16)svd_up[(r0 + r) * RANK + k];
  }
}

__device__ inline void stage_d(const unsigned int* __restrict__ dp, unsigned int (*Dl)[128],
                               int tid, int kt) {
  int c = (tid & 31) * 4;
#pragma unroll
  for (int i = 0; i < 8; i++) {
    int r2 = i * 8 + (tid >> 5);
    *(v4u*)&Dl[r2][c] = *(const v4u*)(dp + r2 * IN_DIM + kt * 128 + c);
  }
}

// C-tile [32 rows][128 cols] = U_tile[32][128] @ D_slice[128][128], f16 MFMA 16x16x32.
__device__ inline void svd_mfma(const _Float16 (*U)[136], const unsigned int (*Dl)[128],
                                int l, int w, v4f acc[2][2]) {
#pragma unroll
  for (int ks = 0; ks < 4; ks++) {
    v8h a0 = *(const v8h*)&U[(l & 15)][ks * 32 + (l >> 4) * 8];
    v8h a1 = *(const v8h*)&U[16 + (l & 15)][ks * 32 + (l >> 4) * 8];
#pragma unroll
    for (int fn = 0; fn < 2; fn++) {
      int col = w * 32 + fn * 16 + (l & 15);
      int rb = ks * 16 + (l >> 4) * 4;
      union { unsigned int u[4]; v8h h; } bu;
      bu.u[0] = Dl[rb][col];
      bu.u[1] = Dl[rb + 1][col];
      bu.u[2] = Dl[rb + 2][col];
      bu.u[3] = Dl[rb + 3][col];
      acc[0][fn] = __builtin_amdgcn_mfma_f32_16x16x32_f16(a0, bu.h, acc[0][fn], 0, 0, 0);
      acc[1][fn] = __builtin_amdgcn_mfma_f32_16x16x32_f16(a1, bu.h, acc[1][fn], 0, 0, 0);
    }
  }
}

// ---------------- K2: per-row max |W_f| -> scale_w ----------------
__global__ __launch_bounds__(256, 2) void rowmax_kernel(const unsigned int* __restrict__ wp,
    const float* __restrict__ scale, const float* __restrict__ zp,
    const float* __restrict__ svd_up, const unsigned int* __restrict__ dp,
    float* __restrict__ sw) {
  __shared__ _Float16 U[32][136];
  __shared__ unsigned int Dl[64][128];
  __shared__ float Cl[32][132];
  int tid = threadIdx.x;
  int r0 = blockIdx.x * 32;
  load_u(svd_up, U, tid, r0);
  int l = tid & 63, w = tid >> 6;
  int myrow = tid >> 3, c0 = (tid & 7) * 16;   // each thread owns 1 row x 16 cols per tile
  float rmax = 0.f;
  __syncthreads();
  for (int kt = 0; kt < 32; kt++) {
    stage_d(dp, Dl, tid, kt);
    __syncthreads();
    v4f acc[2][2] = {};
    svd_mfma(U, Dl, l, w, acc);
#pragma unroll
    for (int fm = 0; fm < 2; fm++)
#pragma unroll
      for (int fn = 0; fn < 2; fn++)
#pragma unroll
        for (int j = 0; j < 4; j++)
          Cl[fm * 16 + (l >> 4) * 4 + j][w * 32 + fn * 16 + (l & 15)] = acc[fm][fn][j];
    __syncthreads();
    float s = scale[(r0 + myrow) * NG + kt];   // KT=128 == group size: one group per tile
    float z = zp[(r0 + myrow) * NG + kt];
    v2u pk = *(const v2u*)(wp + (r0 + myrow) * (IN_DIM / 8) + (kt * 128 + c0) / 8);
#pragma unroll
    for (int i = 0; i < 4; i++) {
      v4f cv = *(const v4f*)&Cl[myrow][c0 + i * 4];
#pragma unroll
      for (int e = 0; e < 4; e++) {
        int j = i * 4 + e;
        int q = (pk[j >> 3] >> (4 * (j & 7))) & 15;
        float W = ((float)q - z) * s + cv[e];
        rmax = fmaxf(rmax, fabsf(W));
      }
    }
    __syncthreads();
  }
  rmax = fmaxf(rmax, __shfl_xor(rmax, 1));
  rmax = fmaxf(rmax, __shfl_xor(rmax, 2));
  rmax = fmaxf(rmax, __shfl_xor(rmax, 4));
  if ((tid & 7) == 0) sw[r0 + myrow] = rmax / 127.0f;
}

// ---------------- K3: quantize W + int8 matmul + epilogue ----------------
__global__ __launch_bounds__(256, 2) void matmul_kernel(const unsigned int* __restrict__ wp,
    const float* __restrict__ scale, const float* __restrict__ zp,
    const float* __restrict__ svd_up, const unsigned int* __restrict__ dp,
    const signed char* __restrict__ xq, const float* __restrict__ sx,
    const float* __restrict__ sw, const float* __restrict__ bias,
    float* __restrict__ out) {
  __shared__ _Float16 U[32][136];
  __shared__ unsigned int Dl[64][128];
  __shared__ float Cl[32][132];
  __shared__ unsigned int W8[32][33];   // 33-dword stride: conflict-friendly b32 reads
  __shared__ float sxl[64];
  int tid = threadIdx.x;
  int r0 = blockIdx.x * 32;
  load_u(svd_up, U, tid, r0);
  if (tid < 64) sxl[tid] = sx[tid];
  int l = tid & 63, w = tid >> 6;
  int myrow = tid >> 3, c0 = (tid & 7) * 16;
  float swr = sw[r0 + myrow];
  v4i oacc[2] = {};
  __syncthreads();
  for (int kt = 0; kt < 32; kt++) {
    stage_d(dp, Dl, tid, kt);
    __syncthreads();
    v4f acc[2][2] = {};
    svd_mfma(U, Dl, l, w, acc);       // identical code to rowmax pass -> same W bits
#pragma unroll
    for (int fm = 0; fm < 2; fm++)
#pragma unroll
      for (int fn = 0; fn < 2; fn++)
#pragma unroll
        for (int j = 0; j < 4; j++)
          Cl[fm * 16 + (l >> 4) * 4 + j][w * 32 + fn * 16 + (l & 15)] = acc[fm][fn][j];
    __syncthreads();
    float s = scale[(r0 + myrow) * NG + kt];
    float z = zp[(r0 + myrow) * NG + kt];
    v2u pk = *(const v2u*)(wp + (r0 + myrow) * (IN_DIM / 8) + (kt * 128 + c0) / 8);
#pragma unroll
    for (int i = 0; i < 4; i++) {
      v4f cv = *(const v4f*)&Cl[myrow][c0 + i * 4];
      int q[4];
#pragma unroll
      for (int e = 0; e < 4; e++) {
        int j = i * 4 + e;
        int qn = (pk[j >> 3] >> (4 * (j & 7))) & 15;
        float W = ((float)qn - z) * s + cv[e];
        float qf = rintf(W / swr);
        qf = fminf(127.f, fmaxf(-128.f, qf));
        q[e] = (int)qf;
      }
      W8[myrow][(c0 >> 2) + i] =
          (q[0] & 255) | ((q[1] & 255) << 8) | ((q[2] & 255) << 16) | ((q[3] & 255) << 24);
    }
    __syncthreads();
    // int8 matmul: wave w owns tokens [w*16, w*16+16); fr in {0,1} row-frags of 16
#pragma unroll
    for (int ks = 0; ks < 2; ks++) {
      v4i a = *(const v4i*)(xq + (w * 16 + (l & 15)) * IN_DIM + kt * 128 + ks * 64 + (l >> 4) * 16);
#pragma unroll
      for (int fr = 0; fr < 2; fr++) {
        int rr = fr * 16 + (l & 15);
        int kd = ks * 16 + (l >> 4) * 4;
        v4i b;
        b[0] = (int)W8[rr][kd];
        b[1] = (int)W8[rr][kd + 1];
        b[2] = (int)W8[rr][kd + 2];
        b[3] = (int)W8[rr][kd + 3];
        oacc[fr] = __builtin_amdgcn_mfma_i32_16x16x64_i8(a, b, oacc[fr], 0, 0, 0);
      }
    }
  }
  // epilogue: out[t,o] = acc * sx[t] * sw[o] + bias[o]
#pragma unroll
  for (int fr = 0; fr < 2; fr++) {
#pragma unroll
    for (int j = 0; j < 4; j++) {
      int token = w * 16 + (l >> 4) * 4 + j;
      int orow = r0 + fr * 16 + (l & 15);
      float v = (float)oacc[fr][j] * sxl[token] * sw[orow] + bias[orow];
      out[token * OUT_DIM + orow] = v;
    }
  }
}

// ---------------- launch ----------------
extern "C" void kernel_launch(void* const* d_in, const int* in_sizes, int n_in,
                              void* d_out, int out_size, void* d_ws, size_t ws_size,
                              hipStream_t stream) {
  (void)in_sizes; (void)n_in; (void)out_size; (void)ws_size;
  const float* x        = (const float*)d_in[0];
  const int*   wq       = (const int*)d_in[1];
  const float* scale    = (const float*)d_in[2];
  const float* zp       = (const float*)d_in[3];
  const float* svd_up   = (const float*)d_in[4];
  const float* svd_down = (const float*)d_in[5];
  const float* bias     = (const float*)d_in[6];
  float* out = (float*)d_out;

  char* ws = (char*)d_ws;
  unsigned int* dp = (unsigned int*)ws;                         // 1,048,576 B : f16-paired svd_down
  signed char*  xq = (signed char*)(ws + 1048576);              //   262,144 B : x int8
  float*        sx = (float*)(ws + 1048576 + 262144);           //       256 B : scale_x
  float*        sw = (float*)(ws + 1048576 + 262144 + 256);     //    44,032 B : scale_w
  unsigned int* wpk = (unsigned int*)(ws + 1048576 + 262144 + 256 + 44032); // 22,544,384 B : 4-bit W

  pack_d_kernel<<<256, 256, 0, stream>>>(svd_down, dp);
  quant_x_kernel<<<NTOK, 256, 0, stream>>>(x, xq, sx);
  repack_w_kernel<<<2048, 256, 0, stream>>>(wq, wpk);
  rowmax_kernel<<<OUT_DIM / 32, 256, 0, stream>>>(wpk, scale, zp, svd_up, dp, sw);
  matmul_kernel<<<OUT_DIM / 32, 256, 0, stream>>>(wpk, scale, zp, svd_up, dp, xq, sx, sw, bias, out);
}

// Round 3
// 352.705 us; speedup vs baseline: 1.1664x; 1.1664x over previous
//
#include <hip/hip_runtime.h>
#include <string.h>

#define OUT_DIM 11008
#define IN_DIM  4096
#define NTOK    64
#define RANK    128
#define NG      32

typedef float        v4f  __attribute__((ext_vector_type(4)));
typedef int          v4i  __attribute__((ext_vector_type(4)));
typedef unsigned int v4u  __attribute__((ext_vector_type(4)));
typedef unsigned int v2u  __attribute__((ext_vector_type(2)));
typedef _Float16     v8h  __attribute__((ext_vector_type(8)));

// ---------------- K0: pack svd_down (f32 [128][4096]) into f16 row-pairs ----------------
// dp[r2*4096 + c] = { D[2*r2][c] (lo), D[2*r2+1][c] (hi) } — f16 MFMA B-fragment order.
__device__ inline unsigned int pack2h(float lo, float hi) {
  union { _Float16 h[2]; unsigned int u; } t;
  t.h[0] = (_Float16)lo; t.h[1] = (_Float16)hi;
  return t.u;
}

__global__ __launch_bounds__(256) void pack_d_kernel(const float* __restrict__ d,
                                                     unsigned int* __restrict__ dp) {
  int idx = (blockIdx.x * 256 + threadIdx.x) * 4;   // dword index
  int r2 = idx >> 12, c = idx & 4095;
  v4f a = *(const v4f*)(d + (2 * r2) * IN_DIM + c);
  v4f b = *(const v4f*)(d + (2 * r2 + 1) * IN_DIM + c);
  v4u o;
#pragma unroll
  for (int e = 0; e < 4; e++) o[e] = pack2h(a[e], b[e]);
  *(v4u*)(dp + idx) = o;
}

// ---------------- helpers for the C-GEMM ----------------
__device__ inline void load_u(const float* __restrict__ svd_up, _Float16 (*U)[136],
                              int tid, int r0) {
#pragma unroll
  for (int i = 0; i < 16; i++) {
    int idx = i * 256 + tid;
    int r = idx >> 7, k = idx & 127;
    U[r][k] = (_Float16)svd_up[(r0 + r) * RANK + k];
  }
}

__device__ inline void stage_d(const unsigned int* __restrict__ dp, unsigned int (*Dl)[128],
                               int tid, int kt) {
  int c = (tid & 31) * 4;
#pragma unroll
  for (int i = 0; i < 8; i++) {
    int r2 = i * 8 + (tid >> 5);
    *(v4u*)&Dl[r2][c] = *(const v4u*)(dp + r2 * IN_DIM + kt * 128 + c);
  }
}

__device__ inline void svd_mfma(const _Float16 (*U)[136], const unsigned int (*Dl)[128],
                                int l, int w, v4f acc[2][2]) {
#pragma unroll
  for (int ks = 0; ks < 4; ks++) {
    v8h a0 = *(const v8h*)&U[(l & 15)][ks * 32 + (l >> 4) * 8];
    v8h a1 = *(const v8h*)&U[16 + (l & 15)][ks * 32 + (l >> 4) * 8];
#pragma unroll
    for (int fn = 0; fn < 2; fn++) {
      int col = w * 32 + fn * 16 + (l & 15);
      int rb = ks * 16 + (l >> 4) * 4;
      union { unsigned int u[4]; v8h h; } bu;
      bu.u[0] = Dl[rb][col];
      bu.u[1] = Dl[rb + 1][col];
      bu.u[2] = Dl[rb + 2][col];
      bu.u[3] = Dl[rb + 3][col];
      acc[0][fn] = __builtin_amdgcn_mfma_f32_16x16x32_f16(a0, bu.h, acc[0][fn], 0, 0, 0);
      acc[1][fn] = __builtin_amdgcn_mfma_f32_16x16x32_f16(a1, bu.h, acc[1][fn], 0, 0, 0);
    }
  }
}

// ---------------- K1: C = svd_up @ svd_down, materialized f16 [OUT][IN] ----------------
__global__ __launch_bounds__(256) void cgemm_kernel(const float* __restrict__ svd_up,
    const unsigned int* __restrict__ dp, _Float16* __restrict__ Cb) {
  __shared__ _Float16 U[32][136];
  __shared__ unsigned int Dl[64][128];
  int tid = threadIdx.x;
  int r0 = blockIdx.x * 32;
  load_u(svd_up, U, tid, r0);
  int l = tid & 63, w = tid >> 6;
  __syncthreads();
  for (int ct = 0; ct < 4; ct++) {
    int ktile = blockIdx.y * 4 + ct;
    stage_d(dp, Dl, tid, ktile);
    __syncthreads();
    v4f acc[2][2] = {};
    svd_mfma(U, Dl, l, w, acc);
#pragma unroll
    for (int fm = 0; fm < 2; fm++)
#pragma unroll
      for (int fn = 0; fn < 2; fn++)
#pragma unroll
        for (int j = 0; j < 4; j++) {
          int row = r0 + fm * 16 + (l >> 4) * 4 + j;
          int col = ktile * 128 + w * 32 + fn * 16 + (l & 15);
          Cb[row * IN_DIM + col] = (_Float16)acc[fm][fn][j];
        }
    __syncthreads();
  }
}

// ---------------- K2: fused repack + rowmax, pure streaming, one wave per row --------
__global__ __launch_bounds__(256) void rowmax_kernel(const int* __restrict__ wq,
    const float* __restrict__ scale, const float* __restrict__ zp,
    const _Float16* __restrict__ Cb, unsigned int* __restrict__ wpk,
    float* __restrict__ swmax) {
  int tid = threadIdx.x;
  int lane = tid & 63, w = tid >> 6;
  int r = blockIdx.x * 4 + w;
  const int* wrow = wq + r * IN_DIM;
  const _Float16* crow = Cb + r * IN_DIM;
  unsigned int* prow = wpk + r * (IN_DIM / 8);
  const float* srow = scale + r * NG;
  const float* zrow = zp + r * NG;
  float m = 0.f;
  for (int j = 0; j < 8; j++) {
    int d = j * 64 + lane;          // dword index in row, 0..511
    int e0 = d * 8;                 // first element of this thread's 8
    v4i w0 = *(const v4i*)(wrow + e0);
    v4i w1 = *(const v4i*)(wrow + e0 + 4);
    union { v4u u; _Float16 h[8]; } cc;
    cc.u = *(const v4u*)(crow + e0);
    int g = e0 >> 7;
    float s = srow[g], z = zrow[g];
    unsigned int o = (unsigned)(w0[0] & 15)         | ((unsigned)(w0[1] & 15) << 4)
                   | ((unsigned)(w0[2] & 15) << 8)  | ((unsigned)(w0[3] & 15) << 12)
                   | ((unsigned)(w1[0] & 15) << 16) | ((unsigned)(w1[1] & 15) << 20)
                   | ((unsigned)(w1[2] & 15) << 24) | ((unsigned)(w1[3] & 15) << 28);
    prow[d] = o;
#pragma unroll
    for (int k = 0; k < 4; k++) {
      m = fmaxf(m, fabsf(((float)w0[k] - z) * s + (float)cc.h[k]));
      m = fmaxf(m, fabsf(((float)w1[k] - z) * s + (float)cc.h[k + 4]));
    }
  }
#pragma unroll
  for (int off = 1; off < 64; off <<= 1) m = fmaxf(m, __shfl_xor(m, off));
  if (lane == 0) swmax[r] = m;
}

// ---------------- K3: dynamic-quantize x per token ----------------
__global__ __launch_bounds__(256) void quant_x_kernel(const float* __restrict__ x,
                                                      signed char* __restrict__ xq,
                                                      float* __restrict__ sx) {
  int t = blockIdx.x, tid = threadIdx.x;
  const float* row = x + t * IN_DIM;
  v4f v[4];
  float m = 0.f;
#pragma unroll
  for (int i = 0; i < 4; i++) {
    v[i] = *(const v4f*)(row + tid * 16 + i * 4);
#pragma unroll
    for (int e = 0; e < 4; e++) m = fmaxf(m, fabsf(v[i][e]));
  }
#pragma unroll
  for (int off = 1; off < 64; off <<= 1) m = fmaxf(m, __shfl_xor(m, off));
  __shared__ float wm[4];
  if ((tid & 63) == 0) wm[tid >> 6] = m;
  __syncthreads();
  m = fmaxf(fmaxf(wm[0], wm[1]), fmaxf(wm[2], wm[3]));
  float s = m / 127.0f;
  if (tid == 0) sx[t] = s;
  unsigned int packed[4];
#pragma unroll
  for (int i = 0; i < 4; i++) {
    int q[4];
#pragma unroll
    for (int e = 0; e < 4; e++) {
      float qf = rintf(v[i][e] / s);
      qf = fminf(127.f, fmaxf(-128.f, qf));
      q[e] = (int)qf;
    }
    packed[i] = (q[0] & 255) | ((q[1] & 255) << 8) | ((q[2] & 255) << 16) | ((q[3] & 255) << 24);
  }
  *(v4u*)(xq + t * IN_DIM + tid * 16) = *(v4u*)packed;
}

// ---------------- K4: quantize W + int8 MFMA, K-split x4, int32 atomic partials ------
__global__ __launch_bounds__(256) void matmul_kernel(const unsigned int* __restrict__ wpk,
    const float* __restrict__ scale, const float* __restrict__ zp,
    const _Float16* __restrict__ Cb, const signed char* __restrict__ xq,
    const float* __restrict__ swmax, int* __restrict__ acc32) {
  __shared__ unsigned int W8[32][33];
  int tid = threadIdx.x;
  int r0 = blockIdx.x * 32;
  int kc = blockIdx.y;                         // K chunk 0..3 (1024 cols each)
  int l = tid & 63, w = tid >> 6;
  int myrow = tid >> 3, c0 = (tid & 7) * 16;
  float swr = swmax[r0 + myrow] / 127.0f;      // exactly ref: max/127
  v4i oacc[2] = {};
  for (int kt = 0; kt < 8; kt++) {
    int kbase = kc * 1024 + kt * 128;
    int g = kbase >> 7;
    float s = scale[(r0 + myrow) * NG + g];
    float z = zp[(r0 + myrow) * NG + g];
    v2u pk = *(const v2u*)(wpk + (r0 + myrow) * (IN_DIM / 8) + ((kbase + c0) >> 3));
    union { v4u u[2]; _Float16 h[16]; } cc;
    cc.u[0] = *(const v4u*)(Cb + (r0 + myrow) * IN_DIM + kbase + c0);
    cc.u[1] = *(const v4u*)(Cb + (r0 + myrow) * IN_DIM + kbase + c0 + 8);
    unsigned int wd[4];
#pragma unroll
    for (int i = 0; i < 4; i++) {
      int q[4];
#pragma unroll
      for (int e = 0; e < 4; e++) {
        int jj = i * 4 + e;
        int qn = (pk[jj >> 3] >> (4 * (jj & 7))) & 15;
        float W = ((float)qn - z) * s + (float)cc.h[jj];   // same expr as rowmax
        float qf = rintf(W / swr);
        qf = fminf(127.f, fmaxf(-128.f, qf));
        q[e] = (int)qf;
      }
      wd[i] = (q[0] & 255) | ((q[1] & 255) << 8) | ((q[2] & 255) << 16) | ((q[3] & 255) << 24);
    }
    __syncthreads();   // previous iteration's MFMA reads of W8 complete
#pragma unroll
    for (int i = 0; i < 4; i++) W8[myrow][(c0 >> 2) + i] = wd[i];
    __syncthreads();
#pragma unroll
    for (int ks = 0; ks < 2; ks++) {
      v4i a = *(const v4i*)(xq + (w * 16 + (l & 15)) * IN_DIM + kbase + ks * 64 + (l >> 4) * 16);
#pragma unroll
      for (int fr = 0; fr < 2; fr++) {
        int rr = fr * 16 + (l & 15);
        int kd = ks * 16 + (l >> 4) * 4;
        v4i b;
        b[0] = (int)W8[rr][kd];
        b[1] = (int)W8[rr][kd + 1];
        b[2] = (int)W8[rr][kd + 2];
        b[3] = (int)W8[rr][kd + 3];
        oacc[fr] = __builtin_amdgcn_mfma_i32_16x16x64_i8(a, b, oacc[fr], 0, 0, 0);
      }
    }
  }
#pragma unroll
  for (int fr = 0; fr < 2; fr++)
#pragma unroll
    for (int j = 0; j < 4; j++) {
      int token = w * 16 + (l >> 4) * 4 + j;
      int orow = r0 + fr * 16 + (l & 15);
      atomicAdd(acc32 + token * OUT_DIM + orow, oacc[fr][j]);  // int32: exact, order-free
    }
}

// ---------------- K5: epilogue — scales + bias ----------------
__global__ __launch_bounds__(256) void epilogue_kernel(const int* __restrict__ acc32,
    const float* __restrict__ sx, const float* __restrict__ swmax,
    const float* __restrict__ bias, float* __restrict__ out) {
  int o = blockIdx.x * 256 + threadIdx.x;
  int t = blockIdx.y;
  float swv = swmax[o] / 127.0f;
  out[t * OUT_DIM + o] = (float)acc32[t * OUT_DIM + o] * sx[t] * swv + bias[o];
}

// ---------------- launch ----------------
extern "C" void kernel_launch(void* const* d_in, const int* in_sizes, int n_in,
                              void* d_out, int out_size, void* d_ws, size_t ws_size,
                              hipStream_t stream) {
  (void)in_sizes; (void)n_in; (void)out_size; (void)ws_size;
  const float* x        = (const float*)d_in[0];
  const int*   wq       = (const int*)d_in[1];
  const float* scale    = (const float*)d_in[2];
  const float* zp       = (const float*)d_in[3];
  const float* svd_up   = (const float*)d_in[4];
  const float* svd_down = (const float*)d_in[5];
  const float* bias     = (const float*)d_in[6];
  float* out = (float*)d_out;

  char* ws = (char*)d_ws;
  unsigned int* dp    = (unsigned int*)(ws);              //  1,048,576 B f16-paired svd_down
  signed char*  xq    = (signed char*)(ws + 1048576);     //    262,144 B x int8
  float*        sx    = (float*)(ws + 1310720);           //        256 B scale_x
  float*        swmax = (float*)(ws + 1310976);           //     44,032 B per-row max|W|
  unsigned int* wpk   = (unsigned int*)(ws + 1355008);    // 22,544,384 B 4-bit W
  _Float16*     Cb    = (_Float16*)(ws + 23899392);       // 90,177,536 B SVD correction f16
  int*          acc32 = (int*)(ws + 114076928);           //  2,818,048 B int32 partials

  pack_d_kernel<<<256, 256, 0, stream>>>(svd_down, dp);
  cgemm_kernel<<<dim3(OUT_DIM / 32, 8), 256, 0, stream>>>(svd_up, dp, Cb);
  rowmax_kernel<<<OUT_DIM / 4, 256, 0, stream>>>(wq, scale, zp, Cb, wpk, swmax);
  quant_x_kernel<<<NTOK, 256, 0, stream>>>(x, xq, sx);
  hipMemsetAsync(acc32, 0, NTOK * OUT_DIM * sizeof(int), stream);
  matmul_kernel<<<dim3(OUT_DIM / 32, 4), 256, 0, stream>>>(wpk, scale, zp, Cb, xq, swmax, acc32);
  epilogue_kernel<<<dim3(OUT_DIM / 256, NTOK), 256, 0, stream>>>(acc32, sx, swmax, bias, out);
}